// Round 4
// baseline (474.975 us; speedup 1.0000x reference)
//
#include <hip/hip_runtime.h>

// ---------------------------------------------------------------------------
// VectorQuantizer R4: fully-fused single-pass design.
//   prep  : E [256][1024] -> ET fp32 [1024][256], ETbf (fragment-linear bf16),
//           norms [1024]
//   fused : 256 blocks x 256 thr; block owns 128 rows (4 waves x 32 rows).
//           A (rows, bf16) in registers; codebook streamed through LDS
//           (16 chunks x 64 codes, double-buffered, global_load_lds 16B).
//           Online argmin + margin-candidate collection; fused exact fp32
//           rescore + gather + out write + loss partial.
//   loss  : sum 256 double partials.
// Exactness: candidates = superset of {codes within MARGIN of bf16-min};
// MARGIN=0.25 > 2*bf16-dot-error bound (~0.08 for this data); epilogue
// filters by final threshold and rescores in fp32 with index tie-break.
// ---------------------------------------------------------------------------

constexpr int Mrows = 32768;
constexpr int Ddim  = 256;
constexpr int Kcode = 1024;

constexpr int   CAP    = 24;
constexpr float MARGIN = 0.25f;

typedef unsigned long long u64;
typedef unsigned short ushort_t;
typedef __attribute__((ext_vector_type(8))) short bf16x8;
typedef __attribute__((ext_vector_type(4))) float f32x4;

__device__ inline u64 packKey(float v, int idx) {
    unsigned u = __float_as_uint(v);
    u = (u & 0x80000000u) ? ~u : (u | 0x80000000u);
    return ((u64)u << 32) | (unsigned)idx;
}
__device__ inline float unpackScore(u64 k) {
    unsigned v = (unsigned)(k >> 32);
    unsigned orig = (v & 0x80000000u) ? (v ^ 0x80000000u) : ~v;
    return __uint_as_float(orig);
}
__device__ inline ushort_t f2bf(float f) {   // RTN-even
    unsigned u = __float_as_uint(f);
    return (ushort_t)((u + 0x7fffu + ((u >> 16) & 1u)) >> 16);
}
__device__ inline void gload_lds16(const void* g, void* l) {
    __builtin_amdgcn_global_load_lds(
        (const __attribute__((address_space(1))) unsigned int*)g,
        (__attribute__((address_space(3))) unsigned int*)l, 16, 0, 0);
}

// ---- prep: block c handles codes [c*64, c*64+64) ----
__global__ __launch_bounds__(256)
void vq_prep(const float* __restrict__ E, float* __restrict__ ET,
             char* __restrict__ ETbf, float* __restrict__ norms) {
    __shared__ float tile[256][64];   // [k][code_local]
    const int t = threadIdx.x;
    const int c = blockIdx.x;

    #pragma unroll
    for (int i = 0; i < 16; ++i) {    // coalesced fp32 loads
        const int k = i * 16 + (t >> 4);
        *(float4*)&tile[k][(t & 15) * 4] =
            *(const float4*)&E[(size_t)k * Kcode + c * 64 + (t & 15) * 4];
    }
    __syncthreads();

    if (t < 64) {                      // norms
        float s = 0.f;
        for (int k = 0; k < 256; ++k) s = fmaf(tile[k][t], tile[k][t], s);
        norms[c * 64 + t] = s;
    }
    // ET fp32 [code][k]
    #pragma unroll
    for (int j = 0; j < 16; ++j) {
        const int cl = t >> 2, k0 = (t & 3) * 64 + j * 4;
        float4 v = {tile[k0][cl], tile[k0 + 1][cl], tile[k0 + 2][cl], tile[k0 + 3][cl]};
        *(float4*)&ET[(size_t)(c * 64 + cl) * Ddim + k0] = v;
    }
    // ETbf fragment-linear: word w = ((g*8+s)*64 + l); lane l holds
    // code = g*16 + (l&15), k = s*32 + (l>>4)*8 + j (8 bf16 = 16 B)
    #pragma unroll
    for (int i = 0; i < 8; ++i) {
        const int wd = i * 256 + t;
        const int g = wd >> 9, s = (wd >> 6) & 7, l = wd & 63;
        const int cl = g * 16 + (l & 15);
        const int k0 = s * 32 + (l >> 4) * 8;
        union { uint4 v; ushort_t u[8]; } pk;
        #pragma unroll
        for (int j = 0; j < 8; ++j) pk.u[j] = f2bf(tile[k0 + j][cl]);
        *(uint4*)(ETbf + (size_t)c * 32768 + (size_t)wd * 16) = pk.v;
    }
}

// ---- fused main ----
__global__ __launch_bounds__(256)
void vq_fused(const float* __restrict__ X, const char* __restrict__ ETbf,
              const float* __restrict__ ET, const float* __restrict__ norms,
              float* __restrict__ out, double* __restrict__ partials) {
    __shared__ __align__(16) char smB[2][32768];
    __shared__ u64   cand[128][CAP];
    __shared__ int   cnt[128];
    __shared__ float thrF[128];
    __shared__ float nrm[1024];
    __shared__ double lred[4];

    const int t = threadIdx.x;
    const int l = t & 63;
    const int w = t >> 6;
    const int blkRow0 = blockIdx.x * 128;
    const int row0 = blkRow0 + w * 32;   // wave's 32 rows

    if (t < 128) cnt[t] = 0;
    #pragma unroll
    for (int i = 0; i < 4; ++i) nrm[i * 256 + t] = norms[i * 256 + t];

    // ---- A fragments: 2 m-frags x 8 k-steps, fp32 -> bf16 in regs ----
    bf16x8 afrag[2][8];
    #pragma unroll
    for (int mi = 0; mi < 2; ++mi)
        #pragma unroll
        for (int s = 0; s < 8; ++s) {
            const float* xp = X + (size_t)(row0 + mi * 16 + (l & 15)) * Ddim
                              + s * 32 + (l >> 4) * 8;
            const float4 v0 = *(const float4*)xp;
            const float4 v1 = *(const float4*)(xp + 4);
            union { bf16x8 v; ushort_t u[8]; } pk;
            pk.u[0] = f2bf(v0.x); pk.u[1] = f2bf(v0.y);
            pk.u[2] = f2bf(v0.z); pk.u[3] = f2bf(v0.w);
            pk.u[4] = f2bf(v1.x); pk.u[5] = f2bf(v1.y);
            pk.u[6] = f2bf(v1.z); pk.u[7] = f2bf(v1.w);
            afrag[mi][s] = pk.v;
        }

    float runmin[2][4], thr[2][4];
    #pragma unroll
    for (int mi = 0; mi < 2; ++mi)
        #pragma unroll
        for (int r = 0; r < 4; ++r) { runmin[mi][r] = 3.4e38f; thr[mi][r] = -3.4e38f; }

    auto STAGE = [&](int c, int buf) {
        const char* src = ETbf + (size_t)c * 32768;
        #pragma unroll
        for (int i = 0; i < 8; ++i)
            gload_lds16(src + (size_t)((i * 256 + t) << 4),
                        smB[buf] + ((i * 256 + (t & ~63)) << 4));
    };

    auto COMPUTE = [&](int c, int buf, bool collect) {
        #pragma unroll
        for (int g = 0; g < 4; ++g) {
            const int col = c * 64 + g * 16 + (l & 15);
            const float nk = nrm[col];
            f32x4 a0 = {0.f, 0.f, 0.f, 0.f}, a1 = {0.f, 0.f, 0.f, 0.f};
            #pragma unroll
            for (int s = 0; s < 8; ++s) {
                const bf16x8 b = *(const bf16x8*)(smB[buf] + ((g * 8 + s) * 64 + l) * 16);
                a0 = __builtin_amdgcn_mfma_f32_16x16x32_bf16(afrag[0][s], b, a0, 0, 0, 0);
                a1 = __builtin_amdgcn_mfma_f32_16x16x32_bf16(afrag[1][s], b, a1, 0, 0, 0);
            }
            #pragma unroll
            for (int mi = 0; mi < 2; ++mi)
                #pragma unroll
                for (int r = 0; r < 4; ++r) {
                    const float sc = fmaf(-2.f, (mi ? a1[r] : a0[r]), nk);
                    if (collect && sc <= thr[mi][r]) {
                        const int rl = w * 32 + mi * 16 + (l >> 4) * 4 + r;
                        const int p = atomicAdd(&cnt[rl], 1);
                        if (p < CAP) cand[rl][p] = packKey(sc, col);
                    }
                    runmin[mi][r] = fminf(runmin[mi][r], sc);
                }
        }
    };
    auto REDUCE_THR = [&]() {
        #pragma unroll
        for (int mi = 0; mi < 2; ++mi)
            #pragma unroll
            for (int r = 0; r < 4; ++r) {
                float m = runmin[mi][r];
                #pragma unroll
                for (int off = 1; off < 16; off <<= 1)
                    m = fminf(m, __shfl_xor(m, off, 16));
                thr[mi][r] = m + MARGIN;
            }
    };

    // ---- pipeline: 16 chunks of 64 codes ----
    STAGE(0, 0);
    __syncthreads();
    STAGE(1, 1);
    COMPUTE(0, 0, false);   // min-only pass (thresholds unknown yet)
    REDUCE_THR();
    COMPUTE(0, 0, true);    // collect pass on chunk 0 (buf still valid)
    REDUCE_THR();
    __syncthreads();        // chunk 1 staged
    for (int c = 1; c < 16; ++c) {
        if (c + 1 < 16) STAGE(c + 1, (c + 1) & 1);
        COMPUTE(c, c & 1, true);
        REDUCE_THR();
        __syncthreads();
    }

    // thr now = final_min + MARGIN
    if ((l & 15) == 0) {
        #pragma unroll
        for (int mi = 0; mi < 2; ++mi)
            #pragma unroll
            for (int r = 0; r < 4; ++r)
                thrF[w * 32 + mi * 16 + (l >> 4) * 4 + r] = thr[mi][r];
    }
    __syncthreads();

    // ---- epilogue: resolve + gather + write + loss (per wave, own 32 rows) --
    double lacc = 0.0;
    for (int rr = 0; rr < 32; ++rr) {
        const int rl = w * 32 + rr;
        const int row = blkRow0 + rl;
        const float4 x4 = *(const float4*)&X[(size_t)row * Ddim + l * 4];
        const float tF = thrF[rl];
        const int n = cnt[rl];

        auto rescoreS = [&](int code) -> float {
            const float4 e4 = *(const float4*)&ET[(size_t)code * Ddim + l * 4];
            float d = x4.x * e4.x;
            d = fmaf(x4.y, e4.y, d);
            d = fmaf(x4.z, e4.z, d);
            d = fmaf(x4.w, e4.w, d);
            #pragma unroll
            for (int off = 1; off < 64; off <<= 1) d += __shfl_xor(d, off, 64);
            return nrm[code] - 2.f * d;
        };

        int code;
        if (n <= CAP) {
            int kept = 0, only = 0;
            for (int j = 0; j < n; ++j) {
                const u64 key = cand[rl][j];
                if (unpackScore(key) <= tF) { only = (int)(key & 0xffffffffu); ++kept; }
            }
            if (kept == 1) {
                code = only;
            } else {
                float bS = 3.4e38f; int bC = 0x7fffffff;
                for (int j = 0; j < n; ++j) {
                    const u64 key = cand[rl][j];
                    if (unpackScore(key) > tF) continue;
                    const int cd = (int)(key & 0xffffffffu);
                    const float s = rescoreS(cd);
                    if (s < bS || (s == bS && cd < bC)) { bS = s; bC = cd; }
                }
                code = bC;
            }
        } else {   // overflow (statistically never): exact full scan
            float bS = 3.4e38f; int bC = 0x7fffffff;
            for (int cd = 0; cd < Kcode; ++cd) {
                const float s = rescoreS(cd);
                if (s < bS || (s == bS && cd < bC)) { bS = s; bC = cd; }
            }
            code = bC;
        }

        const float4 q4 = *(const float4*)&ET[(size_t)code * Ddim + l * 4];
        *(float4*)&out[(size_t)row * Ddim + l * 4] = q4;
        const double dx = (double)(q4.x - x4.x), dy = (double)(q4.y - x4.y);
        const double dz = (double)(q4.z - x4.z), dw = (double)(q4.w - x4.w);
        lacc += dx * dx + dy * dy + dz * dz + dw * dw;
    }
    #pragma unroll
    for (int off = 32; off; off >>= 1) lacc += __shfl_down(lacc, off, 64);
    if (l == 0) lred[w] = lacc;
    __syncthreads();
    if (t == 0)
        partials[blockIdx.x] = lred[0] + lred[1] + lred[2] + lred[3];
}

// ---- final loss ----
__global__ __launch_bounds__(256)
void vq_lossk(const double* __restrict__ partials, float* __restrict__ lossOut) {
    __shared__ double red[4];
    double v = partials[threadIdx.x];
    #pragma unroll
    for (int off = 32; off; off >>= 1) v += __shfl_down(v, off, 64);
    const int lane = threadIdx.x & 63, grp = threadIdx.x >> 6;
    if (lane == 0) red[grp] = v;
    __syncthreads();
    if (threadIdx.x == 0)
        lossOut[0] = (float)(1.25 * (red[0] + red[1] + red[2] + red[3]) /
                             (double)((size_t)Mrows * Ddim));
}

// ===========================================================================
extern "C" void kernel_launch(void* const* d_in, const int* in_sizes, int n_in,
                              void* d_out, int out_size, void* d_ws, size_t ws_size,
                              hipStream_t stream) {
    const float* X = (const float*)d_in[0];
    const float* E = (const float*)d_in[1];
    float* out = (float*)d_out;
    char* ws = (char*)d_ws;

    // workspace layout (8-byte first): partials | ET | ETbf | norms
    const size_t partB = 256 * 8;                      //   2 KB
    const size_t etB   = (size_t)Kcode * Ddim * 4;     //   1 MB
    const size_t etbfB = (size_t)Kcode * Ddim * 2;     // 0.5 MB
    char* p = ws;
    double* partials = (double*)p;  p += partB;
    float*  ET       = (float*)p;   p += etB;
    char*   ETbf     = p;           p += etbfB;
    float*  norms    = (float*)p;

    vq_prep<<<16, 256, 0, stream>>>(E, ET, ETbf, norms);
    vq_fused<<<Mrows / 128, 256, 0, stream>>>(X, ETbf, ET, norms, out, partials);
    vq_lossk<<<1, 256, 0, stream>>>(partials, out + (size_t)Mrows * Ddim);
}

// Round 5
// 434.733 us; speedup vs baseline: 1.0926x; 1.0926x over previous
//
#include <hip/hip_runtime.h>

// ---------------------------------------------------------------------------
// VectorQuantizer R5: barrier-free MFMA scoring with per-lane top-2 tracking.
//   prep  : E [256][1024] -> ET fp32 [1024][256], ETbf fragment-linear bf16,
//           norms [1024]  (verified in R4)
//   fused : 1024 blocks x 256 thr. Wave = 16 rows x 512 codes (2 code-splits
//           per block). A-frags in registers; B-frags loaded straight from
//           global (L2-resident 512KB codebook). No barriers/LDS/atomics in
//           the hot loop. Per-lane top-2 candidate registers + escalation
//           bits make the candidate set a provable superset of
//           {codes within MARGIN of bf16-min}. Uniform resolve epilogue:
//           exact fp32 rescore of candidates, gather, out write, loss.
//   loss  : sum 1024 double partials.
// Exactness: MARGIN=0.25 > 2*bf16-score-error bound (~0.14 for this data);
// escalated lanes' 32-code subsets are fully fp32-rescanned, covering any
// score their top-2 registers dropped.
// ---------------------------------------------------------------------------

constexpr int Mrows = 32768;
constexpr int Ddim  = 256;
constexpr int Kcode = 1024;

constexpr int   CAP    = 8;
constexpr float MARGIN = 0.25f;

typedef unsigned long long u64;
typedef unsigned short ushort_t;
typedef __attribute__((ext_vector_type(8))) short bf16x8;
typedef __attribute__((ext_vector_type(4))) float f32x4;

__device__ inline u64 packKey(float v, int idx) {
    unsigned u = __float_as_uint(v);
    u = (u & 0x80000000u) ? ~u : (u | 0x80000000u);   // order-preserving
    return ((u64)u << 32) | (unsigned)idx;
}
__device__ inline float unpackScore(u64 k) {
    unsigned v = (unsigned)(k >> 32);
    unsigned orig = (v & 0x80000000u) ? (v ^ 0x80000000u) : ~v;
    return __uint_as_float(orig);
}
__device__ inline ushort_t f2bf(float f) {   // RTN-even
    unsigned u = __float_as_uint(f);
    return (ushort_t)((u + 0x7fffu + ((u >> 16) & 1u)) >> 16);
}

// ---- prep: block c handles codes [c*64, c*64+64)  (verified in R4) ----
__global__ __launch_bounds__(256)
void vq_prep(const float* __restrict__ E, float* __restrict__ ET,
             char* __restrict__ ETbf, float* __restrict__ norms) {
    __shared__ float tile[256][64];   // [k][code_local]
    const int t = threadIdx.x;
    const int c = blockIdx.x;

    #pragma unroll
    for (int i = 0; i < 16; ++i) {
        const int k = i * 16 + (t >> 4);
        *(float4*)&tile[k][(t & 15) * 4] =
            *(const float4*)&E[(size_t)k * Kcode + c * 64 + (t & 15) * 4];
    }
    __syncthreads();

    if (t < 64) {
        float s = 0.f;
        for (int k = 0; k < 256; ++k) s = fmaf(tile[k][t], tile[k][t], s);
        norms[c * 64 + t] = s;
    }
    #pragma unroll
    for (int j = 0; j < 16; ++j) {
        const int cl = t >> 2, k0 = (t & 3) * 64 + j * 4;
        float4 v = {tile[k0][cl], tile[k0 + 1][cl], tile[k0 + 2][cl], tile[k0 + 3][cl]};
        *(float4*)&ET[(size_t)(c * 64 + cl) * Ddim + k0] = v;
    }
    // ETbf fragment-linear: word wd = (g*8+s)*64 + l within chunk c; lane l
    // holds code = c*64 + g*16 + (l&15), k = s*32 + (l>>4)*8 (8 bf16 = 16B)
    #pragma unroll
    for (int i = 0; i < 8; ++i) {
        const int wd = i * 256 + t;
        const int g = wd >> 9, s = (wd >> 6) & 7, l = wd & 63;
        const int cl = g * 16 + (l & 15);
        const int k0 = s * 32 + (l >> 4) * 8;
        union { uint4 v; ushort_t u[8]; } pk;
        #pragma unroll
        for (int j = 0; j < 8; ++j) pk.u[j] = f2bf(tile[k0 + j][cl]);
        *(uint4*)(ETbf + (size_t)c * 32768 + (size_t)wd * 16) = pk.v;
    }
}

// ---- fused main: no barriers in the hot loop ----
__global__ __launch_bounds__(256, 3)
void vq_fused(const float* __restrict__ X, const char* __restrict__ ETbf,
              const float* __restrict__ ET, const float* __restrict__ norms,
              float* __restrict__ out, double* __restrict__ partials) {
    __shared__ float    nrm[1024];
    __shared__ u64      cand[32][CAP];
    __shared__ int      cnt[32];
    __shared__ unsigned escal[32];
    __shared__ float    rowminS[32][2];
    __shared__ double   lred[4];

    const int t = threadIdx.x;
    const int l = t & 63;
    const int w = t >> 6;
    const int rg = w >> 1;          // row-group 0/1 (16 rows each)
    const int s2 = w & 1;           // code-split 0/1 (512 codes each)
    const int l15 = l & 15, lq = l >> 4;
    const int row0 = blockIdx.x * 32 + rg * 16;

    if (t < 32) { cnt[t] = 0; escal[t] = 0; }
    #pragma unroll
    for (int i = 0; i < 4; ++i) nrm[i * 256 + t] = norms[i * 256 + t];

    // ---- A fragments: 16 rows x K=256, fp32 -> bf16 in regs ----
    bf16x8 afrag[8];
    #pragma unroll
    for (int s = 0; s < 8; ++s) {
        const float* xp = X + (size_t)(row0 + l15) * Ddim + s * 32 + lq * 8;
        const float4 v0 = *(const float4*)xp;
        const float4 v1 = *(const float4*)(xp + 4);
        union { bf16x8 v; ushort_t u[8]; } pk;
        pk.u[0] = f2bf(v0.x); pk.u[1] = f2bf(v0.y);
        pk.u[2] = f2bf(v0.z); pk.u[3] = f2bf(v0.w);
        pk.u[4] = f2bf(v1.x); pk.u[5] = f2bf(v1.y);
        pk.u[6] = f2bf(v1.z); pk.u[7] = f2bf(v1.w);
        afrag[s] = pk.v;
    }

    u64 b1k[4], b2k[4];
    #pragma unroll
    for (int r = 0; r < 4; ++r) { b1k[r] = ~0ULL; b2k[r] = ~0ULL; }

    __syncthreads();   // nrm ready

    // ---- hot loop: 32 n-frag groups of 16 codes, 2 per iteration ----
    for (int gp = 0; gp < 32; gp += 2) {
        const int G0 = s2 * 32 + gp, G1 = G0 + 1;
        const char* pA = ETbf + (size_t)(G0 >> 2) * 32768
                         + ((size_t)(G0 & 3) * 8 * 64 + l) * 16;
        const char* pB = ETbf + (size_t)(G1 >> 2) * 32768
                         + ((size_t)(G1 & 3) * 8 * 64 + l) * 16;
        bf16x8 bA[8], bB[8];
        #pragma unroll
        for (int s = 0; s < 8; ++s) {
            bA[s] = *(const bf16x8*)(pA + s * 1024);
            bB[s] = *(const bf16x8*)(pB + s * 1024);
        }
        f32x4 aA = {0.f, 0.f, 0.f, 0.f}, aB = {0.f, 0.f, 0.f, 0.f};
        #pragma unroll
        for (int s = 0; s < 8; ++s) {
            aA = __builtin_amdgcn_mfma_f32_16x16x32_bf16(afrag[s], bA[s], aA, 0, 0, 0);
            aB = __builtin_amdgcn_mfma_f32_16x16x32_bf16(afrag[s], bB[s], aB, 0, 0, 0);
        }
        const float nkA = nrm[G0 * 16 + l15];
        const float nkB = nrm[G1 * 16 + l15];
        #pragma unroll
        for (int r = 0; r < 4; ++r) {
            const u64 kA = packKey(fmaf(-2.f, aA[r], nkA), G0 * 16 + l15);
            if (kA < b1k[r])      { b2k[r] = b1k[r]; b1k[r] = kA; }
            else if (kA < b2k[r]) { b2k[r] = kA; }
            const u64 kB = packKey(fmaf(-2.f, aB[r], nkB), G1 * 16 + l15);
            if (kB < b1k[r])      { b2k[r] = b1k[r]; b1k[r] = kB; }
            else if (kB < b2k[r]) { b2k[r] = kB; }
        }
    }

    // ---- emission: one shuffle row-min, candidates/escalation to LDS ----
    #pragma unroll
    for (int r = 0; r < 4; ++r) {
        u64 m = b1k[r];
        #pragma unroll
        for (int off = 1; off < 16; off <<= 1) {
            const u64 o = __shfl_xor(m, off, 16);
            if (o < m) m = o;
        }
        const float rmin = unpackScore(m);
        const int rowL = rg * 16 + lq * 4 + r;
        if (l15 == 0) rowminS[rowL][s2] = rmin;
        const float thr = rmin + MARGIN;
        if (unpackScore(b2k[r]) <= thr) {
            // lane may have dropped a 3rd within-margin score -> escalate
            atomicOr(&escal[rowL], 1u << (l15 + s2 * 16));
        } else if (unpackScore(b1k[r]) <= thr) {
            const int p = atomicAdd(&cnt[rowL], 1);
            if (p < CAP) cand[rowL][p] = b1k[r];
        }
    }
    __syncthreads();

    // ---- resolve epilogue: wave handles 8 rows ----
    double lacc = 0.0;
    for (int rr = 0; rr < 8; ++rr) {
        const int rowL = w * 8 + rr;
        const int row = blockIdx.x * 32 + rowL;
        const float4 x4 = *(const float4*)&X[(size_t)row * Ddim + l * 4];
        const float thr = fminf(rowminS[rowL][0], rowminS[rowL][1]) + MARGIN;
        const unsigned em = escal[rowL];
        const int n = cnt[rowL];

        auto rescoreS = [&](int code) -> float {
            const float4 e4 = *(const float4*)&ET[(size_t)code * Ddim + l * 4];
            float d = x4.x * e4.x;
            d = fmaf(x4.y, e4.y, d);
            d = fmaf(x4.z, e4.z, d);
            d = fmaf(x4.w, e4.w, d);
            #pragma unroll
            for (int off = 1; off < 64; off <<= 1) d += __shfl_xor(d, off, 64);
            return nrm[code] - 2.f * d;
        };

        int code;
        if (n <= CAP && em == 0) {
            int kept = 0, only = 0;
            for (int j = 0; j < n; ++j) {
                const u64 key = cand[rowL][j];
                if (unpackScore(key) <= thr) { only = (int)(key & 0xffffffffu); ++kept; }
            }
            if (kept == 1) {
                code = only;   // unique within-margin candidate: exact
            } else {
                float bS = 3.4e38f; int bC = 0x7fffffff;
                for (int j = 0; j < n; ++j) {
                    const u64 key = cand[rowL][j];
                    if (unpackScore(key) > thr) continue;
                    const int cd = (int)(key & 0xffffffffu);
                    const float s = rescoreS(cd);
                    if (s < bS || (s == bS && cd < bC)) { bS = s; bC = cd; }
                }
                code = bC;
            }
        } else if (n <= CAP) {
            float bS = 3.4e38f; int bC = 0x7fffffff;
            for (int j = 0; j < n; ++j) {
                const u64 key = cand[rowL][j];
                if (unpackScore(key) > thr) continue;
                const int cd = (int)(key & 0xffffffffu);
                const float s = rescoreS(cd);
                if (s < bS || (s == bS && cd < bC)) { bS = s; bC = cd; }
            }
            unsigned m2 = em;
            while (m2) {      // escalated lanes: fp32 rescan their 32-code subset
                const int bit = __ffs(m2) - 1; m2 &= m2 - 1;
                const int sp = bit >> 4, c15 = bit & 15;
                for (int g = 0; g < 32; ++g) {
                    const int cd = sp * 512 + g * 16 + c15;
                    const float s = rescoreS(cd);
                    if (s < bS || (s == bS && cd < bC)) { bS = s; bC = cd; }
                }
            }
            code = bC;
        } else {              // candidate-list overflow: exact full scan
            float bS = 3.4e38f; int bC = 0x7fffffff;
            for (int cd = 0; cd < Kcode; ++cd) {
                const float s = rescoreS(cd);
                if (s < bS || (s == bS && cd < bC)) { bS = s; bC = cd; }
            }
            code = bC;
        }

        const float4 q4 = *(const float4*)&ET[(size_t)code * Ddim + l * 4];
        *(float4*)&out[(size_t)row * Ddim + l * 4] = q4;
        const double dx = (double)(q4.x - x4.x), dy = (double)(q4.y - x4.y);
        const double dz = (double)(q4.z - x4.z), dw = (double)(q4.w - x4.w);
        lacc += dx * dx + dy * dy + dz * dz + dw * dw;
    }
    #pragma unroll
    for (int off = 32; off; off >>= 1) lacc += __shfl_down(lacc, off, 64);
    if (l == 0) lred[w] = lacc;
    __syncthreads();
    if (t == 0)
        partials[blockIdx.x] = lred[0] + lred[1] + lred[2] + lred[3];
}

// ---- final loss ----
__global__ __launch_bounds__(256)
void vq_lossk(const double* __restrict__ partials, float* __restrict__ lossOut) {
    __shared__ double red[4];
    double v = 0.0;
    for (int i = threadIdx.x; i < 1024; i += 256) v += partials[i];
    #pragma unroll
    for (int off = 32; off; off >>= 1) v += __shfl_down(v, off, 64);
    const int lane = threadIdx.x & 63, grp = threadIdx.x >> 6;
    if (lane == 0) red[grp] = v;
    __syncthreads();
    if (threadIdx.x == 0)
        lossOut[0] = (float)(1.25 * (red[0] + red[1] + red[2] + red[3]) /
                             (double)((size_t)Mrows * Ddim));
}

// ===========================================================================
extern "C" void kernel_launch(void* const* d_in, const int* in_sizes, int n_in,
                              void* d_out, int out_size, void* d_ws, size_t ws_size,
                              hipStream_t stream) {
    const float* X = (const float*)d_in[0];
    const float* E = (const float*)d_in[1];
    float* out = (float*)d_out;
    char* ws = (char*)d_ws;

    // workspace: partials (8KB) | ET fp32 (1MB) | ETbf (512KB) | norms (4KB)
    const size_t partB = 1024 * 8;
    const size_t etB   = (size_t)Kcode * Ddim * 4;
    const size_t etbfB = (size_t)Kcode * Ddim * 2;
    char* p = ws;
    double* partials = (double*)p;  p += partB;
    float*  ET       = (float*)p;   p += etB;
    char*   ETbf     = p;           p += etbfB;
    float*  norms    = (float*)p;

    vq_prep<<<16, 256, 0, stream>>>(E, ET, ETbf, norms);
    vq_fused<<<Mrows / 32, 256, 0, stream>>>(X, ETbf, ET, norms, out, partials);
    vq_lossk<<<1, 256, 0, stream>>>(partials, out + (size_t)Mrows * Ddim);
}

// Round 6
// 428.171 us; speedup vs baseline: 1.1093x; 1.0153x over previous
//
#include <hip/hip_runtime.h>

// ---------------------------------------------------------------------------
// VectorQuantizer R6: R5 structure (barrier-free MFMA scoring, per-lane
// top-2 + escalation, fused resolve/gather/loss) with a register plan that
// fits under 128 VGPRs (R5 spilled: VGPR_Count=52 < live state).
//   - tracking in f32+int (b1v/b1i/b2v) instead of u64 keys
//   - one 16-code group per hot-loop iteration (8 transient b-frags)
//   - __launch_bounds__(256,4): cap 128 VGPRs, 4 waves/SIMD guaranteed
// Exactness: MARGIN=0.25 > 2*bf16-score-error bound (~0.14 for this data);
// candidates pushed with split-local threshold (superset of final); lanes
// whose 2nd-best is within threshold escalate -> their 32-code subset is
// fully fp32-rescanned; final filter + fp32 rescore with index tie-break.
// ---------------------------------------------------------------------------

constexpr int Mrows = 32768;
constexpr int Ddim  = 256;
constexpr int Kcode = 1024;

constexpr int   CAP    = 8;
constexpr float MARGIN = 0.25f;

typedef unsigned long long u64;
typedef unsigned short ushort_t;
typedef __attribute__((ext_vector_type(8))) short bf16x8;
typedef __attribute__((ext_vector_type(4))) float f32x4;

__device__ inline u64 packKey(float v, int idx) {
    unsigned u = __float_as_uint(v);
    u = (u & 0x80000000u) ? ~u : (u | 0x80000000u);   // order-preserving
    return ((u64)u << 32) | (unsigned)idx;
}
__device__ inline float unpackScore(u64 k) {
    unsigned v = (unsigned)(k >> 32);
    unsigned orig = (v & 0x80000000u) ? (v ^ 0x80000000u) : ~v;
    return __uint_as_float(orig);
}
__device__ inline ushort_t f2bf(float f) {   // RTN-even
    unsigned u = __float_as_uint(f);
    return (ushort_t)((u + 0x7fffu + ((u >> 16) & 1u)) >> 16);
}

// ---- prep: block c handles codes [c*64, c*64+64)  (verified R4/R5) ----
__global__ __launch_bounds__(256)
void vq_prep(const float* __restrict__ E, float* __restrict__ ET,
             char* __restrict__ ETbf, float* __restrict__ norms) {
    __shared__ float tile[256][64];   // [k][code_local]
    const int t = threadIdx.x;
    const int c = blockIdx.x;

    #pragma unroll
    for (int i = 0; i < 16; ++i) {
        const int k = i * 16 + (t >> 4);
        *(float4*)&tile[k][(t & 15) * 4] =
            *(const float4*)&E[(size_t)k * Kcode + c * 64 + (t & 15) * 4];
    }
    __syncthreads();

    if (t < 64) {
        float s = 0.f;
        for (int k = 0; k < 256; ++k) s = fmaf(tile[k][t], tile[k][t], s);
        norms[c * 64 + t] = s;
    }
    #pragma unroll
    for (int j = 0; j < 16; ++j) {
        const int cl = t >> 2, k0 = (t & 3) * 64 + j * 4;
        float4 v = {tile[k0][cl], tile[k0 + 1][cl], tile[k0 + 2][cl], tile[k0 + 3][cl]};
        *(float4*)&ET[(size_t)(c * 64 + cl) * Ddim + k0] = v;
    }
    // ETbf fragment-linear: byte offset (G*8+s)*1024 + l*16; lane l holds
    // code = G*16 + (l&15), k = s*32 + (l>>4)*8 + j  (8 bf16 = 16B)
    #pragma unroll
    for (int i = 0; i < 8; ++i) {
        const int wd = i * 256 + t;
        const int g = wd >> 9, s = (wd >> 6) & 7, l = wd & 63;
        const int cl = g * 16 + (l & 15);
        const int k0 = s * 32 + (l >> 4) * 8;
        union { uint4 v; ushort_t u[8]; } pk;
        #pragma unroll
        for (int j = 0; j < 8; ++j) pk.u[j] = f2bf(tile[k0 + j][cl]);
        *(uint4*)(ETbf + (size_t)c * 32768 + (size_t)wd * 16) = pk.v;
    }
}

// ---- fused main: no barriers in the hot loop ----
__global__ __launch_bounds__(256, 4)
void vq_fused(const float* __restrict__ X, const char* __restrict__ ETbf,
              const float* __restrict__ ET, const float* __restrict__ norms,
              float* __restrict__ out, double* __restrict__ partials) {
    __shared__ float    nrm[1024];
    __shared__ u64      cand[32][CAP];
    __shared__ int      cnt[32];
    __shared__ unsigned escal[32];
    __shared__ float    rowminS[32][2];
    __shared__ double   lred[4];

    const int t = threadIdx.x;
    const int l = t & 63;
    const int w = t >> 6;
    const int rg = w >> 1;          // row-group 0/1 (16 rows each)
    const int s2 = w & 1;           // code-split 0/1 (512 codes each)
    const int l15 = l & 15, lq = l >> 4;
    const int row0 = blockIdx.x * 32 + rg * 16;

    if (t < 32) { cnt[t] = 0; escal[t] = 0; }
    #pragma unroll
    for (int i = 0; i < 4; ++i) nrm[i * 256 + t] = norms[i * 256 + t];

    // ---- A fragments: 16 rows x K=256, fp32 -> bf16 in regs (32 VGPRs) ----
    bf16x8 afrag[8];
    #pragma unroll
    for (int s = 0; s < 8; ++s) {
        const float* xp = X + (size_t)(row0 + l15) * Ddim + s * 32 + lq * 8;
        const float4 v0 = *(const float4*)xp;
        const float4 v1 = *(const float4*)(xp + 4);
        union { bf16x8 v; ushort_t u[8]; } pk;
        pk.u[0] = f2bf(v0.x); pk.u[1] = f2bf(v0.y);
        pk.u[2] = f2bf(v0.z); pk.u[3] = f2bf(v0.w);
        pk.u[4] = f2bf(v1.x); pk.u[5] = f2bf(v1.y);
        pk.u[6] = f2bf(v1.z); pk.u[7] = f2bf(v1.w);
        afrag[s] = pk.v;
    }

    float b1v[4], b2v[4];
    int   b1i[4];
    #pragma unroll
    for (int r = 0; r < 4; ++r) { b1v[r] = 3.4e38f; b2v[r] = 3.4e38f; b1i[r] = 0; }

    __syncthreads();   // nrm ready

    // ---- hot loop: 32 groups of 16 codes; ETbf linear in (G*8+s) ----
    const char* pB = ETbf + (size_t)(s2 * 32) * 8192 + (size_t)l * 16;
    for (int g = 0; g < 32; ++g) {
        bf16x8 b[8];
        #pragma unroll
        for (int s = 0; s < 8; ++s) b[s] = *(const bf16x8*)(pB + s * 1024);
        pB += 8192;
        f32x4 acc = {0.f, 0.f, 0.f, 0.f};
        #pragma unroll
        for (int s = 0; s < 8; ++s)
            acc = __builtin_amdgcn_mfma_f32_16x16x32_bf16(afrag[s], b[s], acc, 0, 0, 0);
        const int code = (s2 * 32 + g) * 16 + l15;
        const float nk = nrm[code];
        #pragma unroll
        for (int r = 0; r < 4; ++r) {
            const float sc = fmaf(-2.f, acc[r], nk);
            if (sc < b1v[r]) { b2v[r] = b1v[r]; b1v[r] = sc; b1i[r] = code; }
            else             { b2v[r] = fminf(b2v[r], sc); }
        }
    }

    // ---- emission: 16-lane row-min, candidates/escalation to LDS ----
    #pragma unroll
    for (int r = 0; r < 4; ++r) {
        float m = b1v[r];
        #pragma unroll
        for (int off = 1; off < 16; off <<= 1)
            m = fminf(m, __shfl_xor(m, off, 16));
        const int rowL = rg * 16 + lq * 4 + r;
        if (l15 == 0) rowminS[rowL][s2] = m;
        const float thr = m + MARGIN;
        if (b2v[r] <= thr) {
            // lane may have dropped a 3rd within-margin score -> escalate
            atomicOr(&escal[rowL], 1u << (l15 + s2 * 16));
        } else if (b1v[r] <= thr) {
            const int p = atomicAdd(&cnt[rowL], 1);
            if (p < CAP) cand[rowL][p] = packKey(b1v[r], b1i[r]);
        }
    }
    __syncthreads();

    // ---- resolve epilogue: wave handles 8 rows ----
    double lacc = 0.0;
    for (int rr = 0; rr < 8; ++rr) {
        const int rowL = w * 8 + rr;
        const int row = blockIdx.x * 32 + rowL;
        const float4 x4 = *(const float4*)&X[(size_t)row * Ddim + l * 4];
        const float thr = fminf(rowminS[rowL][0], rowminS[rowL][1]) + MARGIN;
        const unsigned em = escal[rowL];
        const int n = cnt[rowL];

        auto rescoreS = [&](int code) -> float {
            const float4 e4 = *(const float4*)&ET[(size_t)code * Ddim + l * 4];
            float d = x4.x * e4.x;
            d = fmaf(x4.y, e4.y, d);
            d = fmaf(x4.z, e4.z, d);
            d = fmaf(x4.w, e4.w, d);
            #pragma unroll
            for (int off = 1; off < 64; off <<= 1) d += __shfl_xor(d, off, 64);
            return nrm[code] - 2.f * d;
        };

        int code;
        if (n <= CAP && em == 0) {
            int kept = 0, only = 0;
            for (int j = 0; j < n; ++j) {
                const u64 key = cand[rowL][j];
                if (unpackScore(key) <= thr) { only = (int)(key & 0xffffffffu); ++kept; }
            }
            if (kept == 1) {
                code = only;   // unique within-margin candidate: exact
            } else {
                float bS = 3.4e38f; int bC = 0x7fffffff;
                for (int j = 0; j < n; ++j) {
                    const u64 key = cand[rowL][j];
                    if (unpackScore(key) > thr) continue;
                    const int cd = (int)(key & 0xffffffffu);
                    const float s = rescoreS(cd);
                    if (s < bS || (s == bS && cd < bC)) { bS = s; bC = cd; }
                }
                code = bC;
            }
        } else if (n <= CAP) {
            float bS = 3.4e38f; int bC = 0x7fffffff;
            for (int j = 0; j < n; ++j) {
                const u64 key = cand[rowL][j];
                if (unpackScore(key) > thr) continue;
                const int cd = (int)(key & 0xffffffffu);
                const float s = rescoreS(cd);
                if (s < bS || (s == bS && cd < bC)) { bS = s; bC = cd; }
            }
            unsigned m2 = em;
            while (m2) {      // escalated lanes: fp32 rescan their 32-code subset
                const int bit = __ffs(m2) - 1; m2 &= m2 - 1;
                const int sp = bit >> 4, c15 = bit & 15;
                for (int g = 0; g < 32; ++g) {
                    const int cd = sp * 512 + g * 16 + c15;
                    const float s = rescoreS(cd);
                    if (s < bS || (s == bS && cd < bC)) { bS = s; bC = cd; }
                }
            }
            code = bC;
        } else {              // candidate-list overflow: exact full scan
            float bS = 3.4e38f; int bC = 0x7fffffff;
            for (int cd = 0; cd < Kcode; ++cd) {
                const float s = rescoreS(cd);
                if (s < bS || (s == bS && cd < bC)) { bS = s; bC = cd; }
            }
            code = bC;
        }

        const float4 q4 = *(const float4*)&ET[(size_t)code * Ddim + l * 4];
        *(float4*)&out[(size_t)row * Ddim + l * 4] = q4;
        const double dx = (double)(q4.x - x4.x), dy = (double)(q4.y - x4.y);
        const double dz = (double)(q4.z - x4.z), dw = (double)(q4.w - x4.w);
        lacc += dx * dx + dy * dy + dz * dz + dw * dw;
    }
    #pragma unroll
    for (int off = 32; off; off >>= 1) lacc += __shfl_down(lacc, off, 64);
    if (l == 0) lred[w] = lacc;
    __syncthreads();
    if (t == 0)
        partials[blockIdx.x] = lred[0] + lred[1] + lred[2] + lred[3];
}

// ---- final loss ----
__global__ __launch_bounds__(256)
void vq_lossk(const double* __restrict__ partials, float* __restrict__ lossOut) {
    __shared__ double red[4];
    double v = 0.0;
    for (int i = threadIdx.x; i < 1024; i += 256) v += partials[i];
    #pragma unroll
    for (int off = 32; off; off >>= 1) v += __shfl_down(v, off, 64);
    const int lane = threadIdx.x & 63, grp = threadIdx.x >> 6;
    if (lane == 0) red[grp] = v;
    __syncthreads();
    if (threadIdx.x == 0)
        lossOut[0] = (float)(1.25 * (red[0] + red[1] + red[2] + red[3]) /
                             (double)((size_t)Mrows * Ddim));
}

// ===========================================================================
extern "C" void kernel_launch(void* const* d_in, const int* in_sizes, int n_in,
                              void* d_out, int out_size, void* d_ws, size_t ws_size,
                              hipStream_t stream) {
    const float* X = (const float*)d_in[0];
    const float* E = (const float*)d_in[1];
    float* out = (float*)d_out;
    char* ws = (char*)d_ws;

    // workspace: partials (8KB) | ET fp32 (1MB) | ETbf (512KB) | norms (4KB)
    const size_t partB = 1024 * 8;
    const size_t etB   = (size_t)Kcode * Ddim * 4;
    const size_t etbfB = (size_t)Kcode * Ddim * 2;
    char* p = ws;
    double* partials = (double*)p;  p += partB;
    float*  ET       = (float*)p;   p += etB;
    char*   ETbf     = p;           p += etbfB;
    float*  norms    = (float*)p;

    vq_prep<<<16, 256, 0, stream>>>(E, ET, ETbf, norms);
    vq_fused<<<Mrows / 32, 256, 0, stream>>>(X, ETbf, ET, norms, out, partials);
    vq_lossk<<<1, 256, 0, stream>>>(partials, out + (size_t)Mrows * Ddim);
}

// Round 7
// 394.971 us; speedup vs baseline: 1.2026x; 1.0841x over previous
//
#include <hip/hip_runtime.h>

// ---------------------------------------------------------------------------
// VectorQuantizer R7: LDS-staged MFMA scoring (R3 structure, fixed).
//   prep  : E [256][1024] -> ET fp32 [1024][256], ETbf fragment-linear bf16,
//           norms [1024]  (verified R4-R6)
//   score : grid dim3(2 splits, 512 row-blocks), 256 thr. Block = 64 rows
//           (4 waves x 16) x 512 codes. A-frags in registers (X read once
//           per split); B double-buffered through LDS in 16 chunks of 32
//           codes via global_load_lds; 1 barrier/chunk. Per-lane top-2 +
//           escalation tracking (verified R5/R6); block-local reduce, meta
//           written to global.
//   merge : per row, combine 2 splits, filter by final thr, exact fp32
//           rescore (+ escalated 32-code subsets / overflow full scan),
//           gather, out write, loss partial.  (verified logic, R5/R6)
//   loss  : sum 2048 double partials.
// Exactness: MARGIN=0.25 > 2*bf16-score-error bound (~0.14 for this data);
// candidate set is a provable superset of {codes within MARGIN of min}.
// ---------------------------------------------------------------------------

constexpr int Mrows = 32768;
constexpr int Ddim  = 256;
constexpr int Kcode = 1024;

constexpr int   CAP    = 8;
constexpr float MARGIN = 0.25f;

typedef unsigned long long u64;
typedef unsigned short ushort_t;
typedef __attribute__((ext_vector_type(8))) short bf16x8;
typedef __attribute__((ext_vector_type(4))) float f32x4;

__device__ inline u64 packKey(float v, int idx) {
    unsigned u = __float_as_uint(v);
    u = (u & 0x80000000u) ? ~u : (u | 0x80000000u);   // order-preserving
    return ((u64)u << 32) | (unsigned)idx;
}
__device__ inline float unpackScore(u64 k) {
    unsigned v = (unsigned)(k >> 32);
    unsigned orig = (v & 0x80000000u) ? (v ^ 0x80000000u) : ~v;
    return __uint_as_float(orig);
}
__device__ inline ushort_t f2bf(float f) {   // RTN-even
    unsigned u = __float_as_uint(f);
    return (ushort_t)((u + 0x7fffu + ((u >> 16) & 1u)) >> 16);
}
__device__ inline void gload_lds16(const void* g, void* l) {
    __builtin_amdgcn_global_load_lds(
        (const __attribute__((address_space(1))) unsigned int*)g,
        (__attribute__((address_space(3))) unsigned int*)l, 16, 0, 0);
}

// ---- prep: block c handles codes [c*64, c*64+64)  (verified R4-R6) ----
__global__ __launch_bounds__(256)
void vq_prep(const float* __restrict__ E, float* __restrict__ ET,
             char* __restrict__ ETbf, float* __restrict__ norms) {
    __shared__ float tile[256][64];   // [k][code_local]
    const int t = threadIdx.x;
    const int c = blockIdx.x;

    #pragma unroll
    for (int i = 0; i < 16; ++i) {
        const int k = i * 16 + (t >> 4);
        *(float4*)&tile[k][(t & 15) * 4] =
            *(const float4*)&E[(size_t)k * Kcode + c * 64 + (t & 15) * 4];
    }
    __syncthreads();

    if (t < 64) {
        float s = 0.f;
        for (int k = 0; k < 256; ++k) s = fmaf(tile[k][t], tile[k][t], s);
        norms[c * 64 + t] = s;
    }
    #pragma unroll
    for (int j = 0; j < 16; ++j) {
        const int cl = t >> 2, k0 = (t & 3) * 64 + j * 4;
        float4 v = {tile[k0][cl], tile[k0 + 1][cl], tile[k0 + 2][cl], tile[k0 + 3][cl]};
        *(float4*)&ET[(size_t)(c * 64 + cl) * Ddim + k0] = v;
    }
    // ETbf fragment-linear: word wd = (G*8+s)*64 + l (G = 16-code group);
    // lane l: code = G*16 + (l&15), k = s*32 + (l>>4)*8 .. +8
    #pragma unroll
    for (int i = 0; i < 8; ++i) {
        const int wd = i * 256 + t;
        const int g = wd >> 9, s = (wd >> 6) & 7, l = wd & 63;
        const int cl = g * 16 + (l & 15);
        const int k0 = s * 32 + (l >> 4) * 8;
        union { uint4 v; ushort_t u[8]; } pk;
        #pragma unroll
        for (int j = 0; j < 8; ++j) pk.u[j] = f2bf(tile[k0 + j][cl]);
        *(uint4*)(ETbf + (size_t)c * 32768 + (size_t)wd * 16) = pk.v;
    }
}

// ---- score: 64 rows x 512 codes per block, LDS double-buffered B ----
__global__ __launch_bounds__(256, 4)
void vq_score(const float* __restrict__ X, const char* __restrict__ ETbf,
              const float* __restrict__ norms,
              float* __restrict__ rowminG, int* __restrict__ cntG,
              unsigned* __restrict__ escG, u64* __restrict__ candG) {
    __shared__ __align__(16) char smB[2][16384];   // 32 codes x 256 dims bf16
    __shared__ float    nrmS[512];
    __shared__ float    rowminS[64];
    __shared__ int      cntS[64];
    __shared__ unsigned escS[64];
    __shared__ u64      candS[64][CAP];

    const int t = threadIdx.x;
    const int l = t & 63;
    const int w = t >> 6;
    const int l15 = l & 15, lq = l >> 4;
    const int split = blockIdx.x;            // 0/1
    const int row0blk = blockIdx.y * 64;

    if (t < 64) { cntS[t] = 0; escS[t] = 0; }
    #pragma unroll
    for (int i = 0; i < 2; ++i)
        nrmS[i * 256 + t] = norms[split * 512 + i * 256 + t];

    // ---- A fragments: wave w owns rows [row0blk + w*16, +16)  (32 VGPRs) --
    bf16x8 afrag[8];
    #pragma unroll
    for (int s = 0; s < 8; ++s) {
        const float* xp = X + (size_t)(row0blk + w * 16 + l15) * Ddim
                          + s * 32 + lq * 8;
        const float4 v0 = *(const float4*)xp;
        const float4 v1 = *(const float4*)(xp + 4);
        union { bf16x8 v; ushort_t u[8]; } pk;
        pk.u[0] = f2bf(v0.x); pk.u[1] = f2bf(v0.y);
        pk.u[2] = f2bf(v0.z); pk.u[3] = f2bf(v0.w);
        pk.u[4] = f2bf(v1.x); pk.u[5] = f2bf(v1.y);
        pk.u[6] = f2bf(v1.z); pk.u[7] = f2bf(v1.w);
        afrag[s] = pk.v;
    }

    float b1v[4], b2v[4];
    int   b1i[4];
    #pragma unroll
    for (int r = 0; r < 4; ++r) { b1v[r] = 3.4e38f; b2v[r] = 3.4e38f; b1i[r] = 0; }

    // ---- double-buffered chunk pipeline: 16 chunks of 32 codes ----
    auto STAGE = [&](int c, int buf) {
        const char* src = ETbf + ((size_t)(split * 16 + c) << 14);
        #pragma unroll
        for (int i = 0; i < 4; ++i)
            gload_lds16(src + (size_t)((i * 256 + t) << 4),
                        smB[buf] + ((i * 256 + (t & ~63)) << 4));
    };

    auto COMPUTE = [&](int c, int buf) {
        #pragma unroll
        for (int g = 0; g < 2; ++g) {
            const char* base = smB[buf] + ((g * 8) * 64 + l) * 16;
            bf16x8 b[8];
            #pragma unroll
            for (int s = 0; s < 8; ++s) b[s] = *(const bf16x8*)(base + s * 1024);
            f32x4 a0 = {0.f, 0.f, 0.f, 0.f}, a1 = {0.f, 0.f, 0.f, 0.f};
            #pragma unroll
            for (int s = 0; s < 8; s += 2) {     // two independent chains
                a0 = __builtin_amdgcn_mfma_f32_16x16x32_bf16(afrag[s], b[s], a0, 0, 0, 0);
                a1 = __builtin_amdgcn_mfma_f32_16x16x32_bf16(afrag[s + 1], b[s + 1], a1, 0, 0, 0);
            }
            const int cloc = c * 32 + g * 16 + l15;
            const float nk = nrmS[cloc];
            const int code = split * 512 + cloc;
            #pragma unroll
            for (int r = 0; r < 4; ++r) {
                const float sc = fmaf(-2.f, a0[r] + a1[r], nk);
                if (sc < b1v[r]) { b2v[r] = b1v[r]; b1v[r] = sc; b1i[r] = code; }
                else             { b2v[r] = fminf(b2v[r], sc); }
            }
        }
    };

    STAGE(0, 0);
    __syncthreads();
    for (int c = 0; c < 16; ++c) {
        if (c < 15) STAGE(c + 1, (c + 1) & 1);
        COMPUTE(c, c & 1);
        __syncthreads();
    }

    // ---- emission: 16-lane row-min, top-2/escalation to LDS ----
    #pragma unroll
    for (int r = 0; r < 4; ++r) {
        float m = b1v[r];
        #pragma unroll
        for (int off = 1; off < 16; off <<= 1)
            m = fminf(m, __shfl_xor(m, off, 16));
        const int rowL = w * 16 + lq * 4 + r;
        if (l15 == 0) rowminS[rowL] = m;
        const float thr = m + MARGIN;
        if (b2v[r] <= thr) {
            atomicOr(&escS[rowL], 1u << l15);   // lane may have dropped a 3rd
        } else if (b1v[r] <= thr) {
            const int p = atomicAdd(&cntS[rowL], 1);
            if (p < CAP) candS[rowL][p] = packKey(b1v[r], b1i[r]);
        }
    }
    __syncthreads();

    // ---- write block meta ----
    const size_t gbase = (size_t)split * Mrows + row0blk;
    if (t < 64) {
        rowminG[gbase + t] = rowminS[t];
        cntG[gbase + t]    = cntS[t];
        escG[gbase + t]    = escS[t];
    }
    for (int e = t; e < 64 * CAP; e += 256) {
        const int rr = e / CAP, j = e % CAP;
        const int n = cntS[rr] < CAP ? cntS[rr] : CAP;
        candG[(gbase + rr) * CAP + j] = (j < n) ? candS[rr][j] : ~0ULL;
    }
}

// ---- merge: filter + exact fp32 rescore + gather + out + loss ----
__global__ __launch_bounds__(256)
void vq_merge(const float* __restrict__ X, const float* __restrict__ ET,
              const float* __restrict__ norms,
              const float* __restrict__ rowminG, const int* __restrict__ cntG,
              const unsigned* __restrict__ escG, const u64* __restrict__ candG,
              float* __restrict__ out, double* __restrict__ partials) {
    __shared__ double lred[4];
    const int t = threadIdx.x;
    const int l = t & 63, w = t >> 6;
    double lacc = 0.0;

    for (int rr = 0; rr < 4; ++rr) {
        const int row = blockIdx.x * 16 + w * 4 + rr;
        const float4 x4 = *(const float4*)&X[(size_t)row * Ddim + l * 4];
        const float thr = fminf(rowminG[row], rowminG[Mrows + row]) + MARGIN;

        auto rescoreS = [&](int code) -> float {
            const float4 e4 = *(const float4*)&ET[(size_t)code * Ddim + l * 4];
            float d = x4.x * e4.x;
            d = fmaf(x4.y, e4.y, d);
            d = fmaf(x4.z, e4.z, d);
            d = fmaf(x4.w, e4.w, d);
            #pragma unroll
            for (int off = 1; off < 64; off <<= 1) d += __shfl_xor(d, off, 64);
            return norms[code] - 2.f * d;
        };

        const int n0 = cntG[row],  n1 = cntG[Mrows + row];
        const unsigned e0 = escG[row], e1 = escG[Mrows + row];

        int code;
        if (n0 <= CAP && n1 <= CAP) {
            // count kept candidates across both splits
            int kept = 0, only = -1;
            for (int sp = 0; sp < 2; ++sp) {
                const int n = sp ? n1 : n0;
                const u64* cl = candG + ((size_t)sp * Mrows + row) * CAP;
                for (int j = 0; j < n; ++j) {
                    const u64 key = cl[j];
                    if (unpackScore(key) <= thr) { only = (int)(key & 0xffffffffu); ++kept; }
                }
            }
            if (kept == 1 && e0 == 0 && e1 == 0) {
                code = only;   // unique within-margin candidate: exact
            } else {
                float bS = 3.4e38f; int bC = 0x7fffffff;
                for (int sp = 0; sp < 2; ++sp) {
                    const int n = sp ? n1 : n0;
                    const u64* cl = candG + ((size_t)sp * Mrows + row) * CAP;
                    for (int j = 0; j < n; ++j) {
                        const u64 key = cl[j];
                        if (unpackScore(key) > thr) continue;
                        const int cd = (int)(key & 0xffffffffu);
                        const float s = rescoreS(cd);
                        if (s < bS || (s == bS && cd < bC)) { bS = s; bC = cd; }
                    }
                    unsigned m2 = sp ? e1 : e0;
                    while (m2) {   // escalated lanes: rescan 32-code subset
                        const int c15 = __ffs(m2) - 1; m2 &= m2 - 1;
                        for (int g = 0; g < 32; ++g) {
                            const int cd = sp * 512 + g * 16 + c15;
                            const float s = rescoreS(cd);
                            if (s < bS || (s == bS && cd < bC)) { bS = s; bC = cd; }
                        }
                    }
                }
                code = bC;
            }
        } else {   // overflow (statistically never): exact full scan
            float bS = 3.4e38f; int bC = 0x7fffffff;
            for (int cd = 0; cd < Kcode; ++cd) {
                const float s = rescoreS(cd);
                if (s < bS || (s == bS && cd < bC)) { bS = s; bC = cd; }
            }
            code = bC;
        }

        const float4 q4 = *(const float4*)&ET[(size_t)code * Ddim + l * 4];
        *(float4*)&out[(size_t)row * Ddim + l * 4] = q4;
        const double dx = (double)(q4.x - x4.x), dy = (double)(q4.y - x4.y);
        const double dz = (double)(q4.z - x4.z), dw = (double)(q4.w - x4.w);
        lacc += dx * dx + dy * dy + dz * dz + dw * dw;
    }
    #pragma unroll
    for (int off = 32; off; off >>= 1) lacc += __shfl_down(lacc, off, 64);
    if (l == 0) lred[w] = lacc;
    __syncthreads();
    if (t == 0)
        partials[blockIdx.x] = lred[0] + lred[1] + lred[2] + lred[3];
}

// ---- final loss ----
__global__ __launch_bounds__(256)
void vq_lossk(const double* __restrict__ partials, float* __restrict__ lossOut) {
    __shared__ double red[4];
    double v = 0.0;
    for (int i = threadIdx.x; i < 2048; i += 256) v += partials[i];
    #pragma unroll
    for (int off = 32; off; off >>= 1) v += __shfl_down(v, off, 64);
    const int lane = threadIdx.x & 63, grp = threadIdx.x >> 6;
    if (lane == 0) red[grp] = v;
    __syncthreads();
    if (threadIdx.x == 0)
        lossOut[0] = (float)(1.25 * (red[0] + red[1] + red[2] + red[3]) /
                             (double)((size_t)Mrows * Ddim));
}

// ===========================================================================
extern "C" void kernel_launch(void* const* d_in, const int* in_sizes, int n_in,
                              void* d_out, int out_size, void* d_ws, size_t ws_size,
                              hipStream_t stream) {
    const float* X = (const float*)d_in[0];
    const float* E = (const float*)d_in[1];
    float* out = (float*)d_out;
    char* ws = (char*)d_ws;

    // workspace: candG 4MB | partials 16KB | ET 1MB | ETbf 512KB |
    //            norms 4KB | rowminG 256KB | cntG 256KB | escG 256KB
    const size_t candB = (size_t)2 * Mrows * CAP * 8;
    const size_t partB = 2048 * 8;
    const size_t etB   = (size_t)Kcode * Ddim * 4;
    const size_t etbfB = (size_t)Kcode * Ddim * 2;
    const size_t nrmB  = (size_t)Kcode * 4;
    const size_t rmB   = (size_t)2 * Mrows * 4;
    char* p = ws;
    u64*      candG    = (u64*)p;      p += candB;
    double*   partials = (double*)p;   p += partB;
    float*    ET       = (float*)p;    p += etB;
    char*     ETbf     = p;            p += etbfB;
    float*    norms    = (float*)p;    p += nrmB;
    float*    rowminG  = (float*)p;    p += rmB;
    int*      cntG     = (int*)p;      p += rmB;
    unsigned* escG     = (unsigned*)p;

    vq_prep<<<16, 256, 0, stream>>>(E, ET, ETbf, norms);
    vq_score<<<dim3(2, Mrows / 64), 256, 0, stream>>>(X, ETbf, norms,
                                                      rowminG, cntG, escG, candG);
    vq_merge<<<Mrows / 16, 256, 0, stream>>>(X, ET, norms, rowminG, cntG, escG,
                                             candG, out, partials);
    vq_lossk<<<1, 256, 0, stream>>>(partials, out + (size_t)Mrows * Ddim);
}

// Round 8
// 88.962 us; speedup vs baseline: 5.3391x; 4.4398x over previous
//
#include <hip/hip_runtime.h>

// ---------------------------------------------------------------------------
// VectorQuantizer R8: single fused kernel over all 1024 codes per block.
// R7 post-mortem: merge's rare full-scan fallback (n>CAP) cost ~350us for a
// single row and set kernel duration (stragglers; same path poisoned R4-R6).
// Fixes:
//   - per-lane top-3 tracking: push b1,b2 (<=thr), escalate only if b3<=thr
//   - CAP=32 == structural max pushes (16 lanes x 2) -> overflow impossible
//   - escalation / fallback rescans are lane-parallel fp32 (cheap)
//   - block sees all 1024 codes -> final threshold at emission, no merge
//     kernel, no candidate/meta global traffic
// Exactness: true argmin c* has bf16 score <= blockmin + 2B (B = bf16 dot
// error << MARGIN/2), so c* is always pushed or its lane escalated. All
// pushed/escalated codes are rescored in exact fp32 with index tie-break.
// ---------------------------------------------------------------------------

constexpr int Mrows = 32768;
constexpr int Ddim  = 256;
constexpr int Kcode = 1024;

constexpr int   CAP    = 32;     // == 16 lanes x 2 pushes: cannot overflow
constexpr float MARGIN = 0.25f;

typedef unsigned long long u64;
typedef unsigned short ushort_t;
typedef __attribute__((ext_vector_type(8))) short bf16x8;
typedef __attribute__((ext_vector_type(4))) float f32x4;

__device__ inline u64 packKey(float v, int idx) {
    unsigned u = __float_as_uint(v);
    u = (u & 0x80000000u) ? ~u : (u | 0x80000000u);   // order-preserving
    return ((u64)u << 32) | (unsigned)idx;
}
__device__ inline float unpackScore(u64 k) {
    unsigned v = (unsigned)(k >> 32);
    unsigned orig = (v & 0x80000000u) ? (v ^ 0x80000000u) : ~v;
    return __uint_as_float(orig);
}
__device__ inline ushort_t f2bf(float f) {   // RTN-even
    unsigned u = __float_as_uint(f);
    return (ushort_t)((u + 0x7fffu + ((u >> 16) & 1u)) >> 16);
}
__device__ inline void gload_lds16(const void* g, void* l) {
    __builtin_amdgcn_global_load_lds(
        (const __attribute__((address_space(1))) unsigned int*)g,
        (__attribute__((address_space(3))) unsigned int*)l, 16, 0, 0);
}

// ---- prep: block c handles codes [c*64, c*64+64)  (verified R4-R7) ----
__global__ __launch_bounds__(256)
void vq_prep(const float* __restrict__ E, float* __restrict__ ET,
             char* __restrict__ ETbf, float* __restrict__ norms) {
    __shared__ float tile[256][64];   // [k][code_local]
    const int t = threadIdx.x;
    const int c = blockIdx.x;

    #pragma unroll
    for (int i = 0; i < 16; ++i) {
        const int k = i * 16 + (t >> 4);
        *(float4*)&tile[k][(t & 15) * 4] =
            *(const float4*)&E[(size_t)k * Kcode + c * 64 + (t & 15) * 4];
    }
    __syncthreads();

    if (t < 64) {
        float s = 0.f;
        for (int k = 0; k < 256; ++k) s = fmaf(tile[k][t], tile[k][t], s);
        norms[c * 64 + t] = s;
    }
    #pragma unroll
    for (int j = 0; j < 16; ++j) {
        const int cl = t >> 2, k0 = (t & 3) * 64 + j * 4;
        float4 v = {tile[k0][cl], tile[k0 + 1][cl], tile[k0 + 2][cl], tile[k0 + 3][cl]};
        *(float4*)&ET[(size_t)(c * 64 + cl) * Ddim + k0] = v;
    }
    // ETbf fragment-linear: group G (16 codes) at byte G*8192 + s*1024 + l*16;
    // lane l: code = G*16 + (l&15), k = s*32 + (l>>4)*8 .. +8
    #pragma unroll
    for (int i = 0; i < 8; ++i) {
        const int wd = i * 256 + t;
        const int g = wd >> 9, s = (wd >> 6) & 7, l = wd & 63;
        const int cl = g * 16 + (l & 15);
        const int k0 = s * 32 + (l >> 4) * 8;
        union { uint4 v; ushort_t u[8]; } pk;
        #pragma unroll
        for (int j = 0; j < 8; ++j) pk.u[j] = f2bf(tile[k0 + j][cl]);
        *(uint4*)(ETbf + (size_t)c * 32768 + (size_t)wd * 16) = pk.v;
    }
}

// ---- fused: 64 rows x all 1024 codes per block; resolve in-block ----
__global__ __launch_bounds__(256, 2)
void vq_fused(const float* __restrict__ X, const char* __restrict__ ETbf,
              const float* __restrict__ ET, const float* __restrict__ norms,
              float* __restrict__ out, double* __restrict__ partials) {
    __shared__ __align__(16) char smB[2][16384];   // 32 codes x 256 dims bf16
    __shared__ float    nrmS[1024];
    __shared__ u64      candS[64][CAP];
    __shared__ int      cntS[64];
    __shared__ unsigned escS[64];
    __shared__ float    rowminS[64];
    __shared__ double   lred[4];

    const int t = threadIdx.x;
    const int l = t & 63;
    const int w = t >> 6;
    const int l15 = l & 15, lq = l >> 4;
    const int row0 = blockIdx.x * 64;

    if (t < 64) { cntS[t] = 0; escS[t] = 0; }
    #pragma unroll
    for (int i = 0; i < 4; ++i) nrmS[i * 256 + t] = norms[i * 256 + t];

    // ---- A fragments: wave w owns rows [row0 + w*16, +16)  (32 VGPRs) ----
    bf16x8 afrag[8];
    #pragma unroll
    for (int s = 0; s < 8; ++s) {
        const float* xp = X + (size_t)(row0 + w * 16 + l15) * Ddim
                          + s * 32 + lq * 8;
        const float4 v0 = *(const float4*)xp;
        const float4 v1 = *(const float4*)(xp + 4);
        union { bf16x8 v; ushort_t u[8]; } pk;
        pk.u[0] = f2bf(v0.x); pk.u[1] = f2bf(v0.y);
        pk.u[2] = f2bf(v0.z); pk.u[3] = f2bf(v0.w);
        pk.u[4] = f2bf(v1.x); pk.u[5] = f2bf(v1.y);
        pk.u[6] = f2bf(v1.z); pk.u[7] = f2bf(v1.w);
        afrag[s] = pk.v;
    }

    // per-lane top-3 tracking (values; indices only for top-2)
    float b1v[4], b2v[4], b3v[4];
    int   b1i[4], b2i[4];
    #pragma unroll
    for (int r = 0; r < 4; ++r) {
        b1v[r] = 3.4e38f; b2v[r] = 3.4e38f; b3v[r] = 3.4e38f;
        b1i[r] = 0; b2i[r] = 0;
    }

    auto STAGE = [&](int c, int buf) {
        const char* src = ETbf + ((size_t)c << 14);
        #pragma unroll
        for (int i = 0; i < 4; ++i)
            gload_lds16(src + (size_t)((i * 256 + t) << 4),
                        smB[buf] + ((i * 256 + (t & ~63)) << 4));
    };

    auto COMPUTE = [&](int c, int buf) {
        #pragma unroll
        for (int g = 0; g < 2; ++g) {
            const char* base = smB[buf] + ((g * 8) * 64 + l) * 16;
            bf16x8 b[8];
            #pragma unroll
            for (int s = 0; s < 8; ++s) b[s] = *(const bf16x8*)(base + s * 1024);
            f32x4 a0 = {0.f, 0.f, 0.f, 0.f}, a1 = {0.f, 0.f, 0.f, 0.f};
            #pragma unroll
            for (int s = 0; s < 8; s += 2) {     // two independent chains
                a0 = __builtin_amdgcn_mfma_f32_16x16x32_bf16(afrag[s], b[s], a0, 0, 0, 0);
                a1 = __builtin_amdgcn_mfma_f32_16x16x32_bf16(afrag[s + 1], b[s + 1], a1, 0, 0, 0);
            }
            const int code = c * 32 + g * 16 + l15;
            const float nk = nrmS[code];
            #pragma unroll
            for (int r = 0; r < 4; ++r) {
                const float sc = fmaf(-2.f, a0[r] + a1[r], nk);
                if (sc < b1v[r]) {
                    b3v[r] = b2v[r]; b2v[r] = b1v[r]; b2i[r] = b1i[r];
                    b1v[r] = sc; b1i[r] = code;
                } else if (sc < b2v[r]) {
                    b3v[r] = b2v[r]; b2v[r] = sc; b2i[r] = code;
                } else if (sc < b3v[r]) {
                    b3v[r] = sc;
                }
            }
        }
    };

    // ---- chunk pipeline: 32 chunks of 32 codes, double-buffered ----
    STAGE(0, 0);
    __syncthreads();
    for (int c = 0; c < 32; ++c) {
        if (c < 31) STAGE(c + 1, (c + 1) & 1);
        COMPUTE(c, c & 1);
        __syncthreads();
    }

    // ---- emission with FINAL block threshold ----
    #pragma unroll
    for (int r = 0; r < 4; ++r) {
        float m = b1v[r];
        #pragma unroll
        for (int off = 1; off < 16; off <<= 1)
            m = fminf(m, __shfl_xor(m, off, 16));
        const int rowL = w * 16 + lq * 4 + r;
        if (l15 == 0) rowminS[rowL] = m;
        const float thr = m + MARGIN;
        if (b1v[r] <= thr) {
            const int p = atomicAdd(&cntS[rowL], 1);
            if (p < CAP) candS[rowL][p] = packKey(b1v[r], b1i[r]);
        }
        if (b2v[r] <= thr) {
            const int p = atomicAdd(&cntS[rowL], 1);
            if (p < CAP) candS[rowL][p] = packKey(b2v[r], b2i[r]);
        }
        if (b3v[r] <= thr)
            atomicOr(&escS[rowL], 1u << l15);   // lane may have dropped a 4th+
    }
    __syncthreads();

    // ---- resolve epilogue: wave handles its own 16 rows ----
    double lacc = 0.0;
    for (int rr = 0; rr < 16; ++rr) {
        const int rowL = w * 16 + rr;
        const int row = row0 + rowL;
        const float4 x4 = *(const float4*)&X[(size_t)row * Ddim + l * 4];
        const int n = cntS[rowL];
        const unsigned em = escS[rowL];

        // shuffle-parallel exact fp32 rescore (one code, all 64 lanes)
        auto rescoreS = [&](int code) -> float {
            const float4 e4 = *(const float4*)&ET[(size_t)code * Ddim + l * 4];
            float d = x4.x * e4.x;
            d = fmaf(x4.y, e4.y, d);
            d = fmaf(x4.z, e4.z, d);
            d = fmaf(x4.w, e4.w, d);
            #pragma unroll
            for (int off = 1; off < 64; off <<= 1) d += __shfl_xor(d, off, 64);
            return nrmS[code] - 2.f * d;
        };
        // per-lane serial exact fp32 score (lane-parallel over codes)
        auto laneDot = [&](int cd) -> float {
            const float* ep = ET + (size_t)cd * Ddim;
            const float* xp = X + (size_t)row * Ddim;
            float s0 = 0.f, s1 = 0.f, s2 = 0.f, s3 = 0.f;
            for (int d0 = 0; d0 < 64; ++d0) {
                const float4 e4 = *(const float4*)(ep + d0 * 4);
                const float4 xx = *(const float4*)(xp + d0 * 4);
                s0 = fmaf(xx.x, e4.x, s0); s1 = fmaf(xx.y, e4.y, s1);
                s2 = fmaf(xx.z, e4.z, s2); s3 = fmaf(xx.w, e4.w, s3);
            }
            return nrmS[cd] - 2.f * ((s0 + s1) + (s2 + s3));
        };

        int code;
        if (n == 1 && em == 0) {
            code = (int)(candS[rowL][0] & 0xffffffffu);   // provably the argmin
        } else if (n >= 1 && n <= CAP) {
            float bS = 3.4e38f; int bC = 0x7fffffff;
            for (int j = 0; j < n; ++j) {
                const int cd = (int)(candS[rowL][j] & 0xffffffffu);
                const float s = rescoreS(cd);
                if (s < bS || (s == bS && cd < bC)) { bS = s; bC = cd; }
            }
            unsigned m2 = em;
            while (m2) {   // escalated lane: rescan its 64 codes, lane-parallel
                const int c15 = __ffs(m2) - 1; m2 &= m2 - 1;
                const int cd = l * 16 + c15;
                u64 k = packKey(laneDot(cd), cd);
                #pragma unroll
                for (int off = 1; off < 64; off <<= 1) {
                    const u64 o = __shfl_xor(k, off, 64);
                    if (o < k) k = o;
                }
                const float s = unpackScore(k);
                const int cd2 = (int)(k & 0xffffffffu);
                if (s < bS || (s == bS && cd2 < bC)) { bS = s; bC = cd2; }
            }
            code = bC;
        } else {   // unreachable (CAP structural); cheap lane-parallel scan
            u64 k = ~0ULL;
            for (int i = 0; i < 16; ++i) {
                const int cd = i * 64 + l;
                const u64 k2 = packKey(laneDot(cd), cd);
                if (k2 < k) k = k2;
            }
            #pragma unroll
            for (int off = 1; off < 64; off <<= 1) {
                const u64 o = __shfl_xor(k, off, 64);
                if (o < k) k = o;
            }
            code = (int)(k & 0xffffffffu);
        }

        const float4 q4 = *(const float4*)&ET[(size_t)code * Ddim + l * 4];
        *(float4*)&out[(size_t)row * Ddim + l * 4] = q4;
        const double dx = (double)(q4.x - x4.x), dy = (double)(q4.y - x4.y);
        const double dz = (double)(q4.z - x4.z), dw = (double)(q4.w - x4.w);
        lacc += dx * dx + dy * dy + dz * dz + dw * dw;
    }
    #pragma unroll
    for (int off = 32; off; off >>= 1) lacc += __shfl_down(lacc, off, 64);
    if (l == 0) lred[w] = lacc;
    __syncthreads();
    if (t == 0)
        partials[blockIdx.x] = lred[0] + lred[1] + lred[2] + lred[3];
}

// ---- final loss ----
__global__ __launch_bounds__(256)
void vq_lossk(const double* __restrict__ partials, float* __restrict__ lossOut) {
    __shared__ double red[4];
    double v = 0.0;
    for (int i = threadIdx.x; i < 512; i += 256) v += partials[i];
    #pragma unroll
    for (int off = 32; off; off >>= 1) v += __shfl_down(v, off, 64);
    const int lane = threadIdx.x & 63, grp = threadIdx.x >> 6;
    if (lane == 0) red[grp] = v;
    __syncthreads();
    if (threadIdx.x == 0)
        lossOut[0] = (float)(1.25 * (red[0] + red[1] + red[2] + red[3]) /
                             (double)((size_t)Mrows * Ddim));
}

// ===========================================================================
extern "C" void kernel_launch(void* const* d_in, const int* in_sizes, int n_in,
                              void* d_out, int out_size, void* d_ws, size_t ws_size,
                              hipStream_t stream) {
    const float* X = (const float*)d_in[0];
    const float* E = (const float*)d_in[1];
    float* out = (float*)d_out;
    char* ws = (char*)d_ws;

    // workspace: partials 4KB | ET 1MB | ETbf 512KB | norms 4KB  (~1.5MB)
    const size_t partB = 512 * 8;
    const size_t etB   = (size_t)Kcode * Ddim * 4;
    const size_t etbfB = (size_t)Kcode * Ddim * 2;
    char* p = ws;
    double* partials = (double*)p;  p += partB;
    float*  ET       = (float*)p;   p += etB;
    char*   ETbf     = p;           p += etbfB;
    float*  norms    = (float*)p;

    vq_prep<<<16, 256, 0, stream>>>(E, ET, ETbf, norms);
    vq_fused<<<Mrows / 64, 256, 0, stream>>>(X, ETbf, ET, norms, out, partials);
    vq_lossk<<<1, 256, 0, stream>>>(partials, out + (size_t)Mrows * Ddim);
}

// Round 9
// 87.629 us; speedup vs baseline: 5.4203x; 1.0152x over previous
//
#include <hip/hip_runtime.h>

// ---------------------------------------------------------------------------
// VectorQuantizer R9: R8 + counted-vmcnt software pipeline (T3+T4).
// R8 post-mortem: per-chunk __syncthreads forces s_waitcnt vmcnt(0) drain;
// at 2 blocks/CU (8 waves) nothing hides the 32 drains -> 83us vs ~30us floor.
// R9 hot loop: 3 LDS buffers, 2-deep prefetch, per phase:
//   s_waitcnt vmcnt(4)   (chunk c landed; chunk c+1 still in flight)
//   s_barrier            (raw -- no compiler drain)
//   STAGE(c+2)           (after barrier: buf[(c+2)%3]==buf[(c-1)%3] is free)
//   COMPUTE(c)
// vmcnt ledger (per wave, in-order retirement): prologue stages 0,1 -> 8
// outstanding; each phase retires 4 (vmcnt(4)) and issues 4; tail 4 -> 0.
// Math/emission/resolve identical to R8 (passed, absmax 9.8e-4).
// ---------------------------------------------------------------------------

constexpr int Mrows = 32768;
constexpr int Ddim  = 256;
constexpr int Kcode = 1024;

constexpr int   CAP    = 32;     // == 16 lanes x 2 pushes: cannot overflow
constexpr float MARGIN = 0.25f;

typedef unsigned long long u64;
typedef unsigned short ushort_t;
typedef __attribute__((ext_vector_type(8))) short bf16x8;
typedef __attribute__((ext_vector_type(4))) float f32x4;

__device__ inline u64 packKey(float v, int idx) {
    unsigned u = __float_as_uint(v);
    u = (u & 0x80000000u) ? ~u : (u | 0x80000000u);   // order-preserving
    return ((u64)u << 32) | (unsigned)idx;
}
__device__ inline float unpackScore(u64 k) {
    unsigned v = (unsigned)(k >> 32);
    unsigned orig = (v & 0x80000000u) ? (v ^ 0x80000000u) : ~v;
    return __uint_as_float(orig);
}
__device__ inline ushort_t f2bf(float f) {   // RTN-even
    unsigned u = __float_as_uint(f);
    return (ushort_t)((u + 0x7fffu + ((u >> 16) & 1u)) >> 16);
}
__device__ inline void gload_lds16(const void* g, void* l) {
    __builtin_amdgcn_global_load_lds(
        (const __attribute__((address_space(1))) unsigned int*)g,
        (__attribute__((address_space(3))) unsigned int*)l, 16, 0, 0);
}

// ---- prep: block c handles codes [c*64, c*64+64)  (verified R4-R8) ----
__global__ __launch_bounds__(256)
void vq_prep(const float* __restrict__ E, float* __restrict__ ET,
             char* __restrict__ ETbf, float* __restrict__ norms) {
    __shared__ float tile[256][64];   // [k][code_local]
    const int t = threadIdx.x;
    const int c = blockIdx.x;

    #pragma unroll
    for (int i = 0; i < 16; ++i) {
        const int k = i * 16 + (t >> 4);
        *(float4*)&tile[k][(t & 15) * 4] =
            *(const float4*)&E[(size_t)k * Kcode + c * 64 + (t & 15) * 4];
    }
    __syncthreads();

    if (t < 64) {
        float s = 0.f;
        for (int k = 0; k < 256; ++k) s = fmaf(tile[k][t], tile[k][t], s);
        norms[c * 64 + t] = s;
    }
    #pragma unroll
    for (int j = 0; j < 16; ++j) {
        const int cl = t >> 2, k0 = (t & 3) * 64 + j * 4;
        float4 v = {tile[k0][cl], tile[k0 + 1][cl], tile[k0 + 2][cl], tile[k0 + 3][cl]};
        *(float4*)&ET[(size_t)(c * 64 + cl) * Ddim + k0] = v;
    }
    // ETbf fragment-linear: group G (16 codes) at byte G*8192 + s*1024 + l*16;
    // lane l: code = G*16 + (l&15), k = s*32 + (l>>4)*8 .. +8
    #pragma unroll
    for (int i = 0; i < 8; ++i) {
        const int wd = i * 256 + t;
        const int g = wd >> 9, s = (wd >> 6) & 7, l = wd & 63;
        const int cl = g * 16 + (l & 15);
        const int k0 = s * 32 + (l >> 4) * 8;
        union { uint4 v; ushort_t u[8]; } pk;
        #pragma unroll
        for (int j = 0; j < 8; ++j) pk.u[j] = f2bf(tile[k0 + j][cl]);
        *(uint4*)(ETbf + (size_t)c * 32768 + (size_t)wd * 16) = pk.v;
    }
}

// ---- fused: 64 rows x all 1024 codes per block; counted-vmcnt pipeline ----
__global__ __launch_bounds__(256, 2)
void vq_fused(const float* __restrict__ X, const char* __restrict__ ETbf,
              const float* __restrict__ ET, const float* __restrict__ norms,
              float* __restrict__ out, double* __restrict__ partials) {
    __shared__ __align__(16) char smB[3][16384];   // 3 bufs x 32 codes x 256 bf16
    __shared__ float    nrmS[1024];
    __shared__ u64      candS[64][CAP];
    __shared__ int      cntS[64];
    __shared__ unsigned escS[64];
    __shared__ float    rowminS[64];
    __shared__ double   lred[4];

    const int t = threadIdx.x;
    const int l = t & 63;
    const int w = t >> 6;
    const int l15 = l & 15, lq = l >> 4;
    const int row0 = blockIdx.x * 64;

    if (t < 64) { cntS[t] = 0; escS[t] = 0; }
    #pragma unroll
    for (int i = 0; i < 4; ++i) nrmS[i * 256 + t] = norms[i * 256 + t];

    // ---- A fragments: wave w owns rows [row0 + w*16, +16)  (32 VGPRs) ----
    bf16x8 afrag[8];
    #pragma unroll
    for (int s = 0; s < 8; ++s) {
        const float* xp = X + (size_t)(row0 + w * 16 + l15) * Ddim
                          + s * 32 + lq * 8;
        const float4 v0 = *(const float4*)xp;
        const float4 v1 = *(const float4*)(xp + 4);
        union { bf16x8 v; ushort_t u[8]; } pk;
        pk.u[0] = f2bf(v0.x); pk.u[1] = f2bf(v0.y);
        pk.u[2] = f2bf(v0.z); pk.u[3] = f2bf(v0.w);
        pk.u[4] = f2bf(v1.x); pk.u[5] = f2bf(v1.y);
        pk.u[6] = f2bf(v1.z); pk.u[7] = f2bf(v1.w);
        afrag[s] = pk.v;
    }

    // per-lane top-3 tracking (values; indices only for top-2)
    float b1v[4], b2v[4], b3v[4];
    int   b1i[4], b2i[4];
    #pragma unroll
    for (int r = 0; r < 4; ++r) {
        b1v[r] = 3.4e38f; b2v[r] = 3.4e38f; b3v[r] = 3.4e38f;
        b1i[r] = 0; b2i[r] = 0;
    }

    auto STAGE = [&](int c, int buf) {
        const char* src = ETbf + ((size_t)c << 14);
        #pragma unroll
        for (int i = 0; i < 4; ++i)
            gload_lds16(src + (size_t)((i * 256 + t) << 4),
                        smB[buf] + ((i * 256 + (t & ~63)) << 4));
    };

    auto COMPUTE = [&](int c, int buf) {
        #pragma unroll
        for (int g = 0; g < 2; ++g) {
            const char* base = smB[buf] + ((g * 8) * 64 + l) * 16;
            bf16x8 b[8];
            #pragma unroll
            for (int s = 0; s < 8; ++s) b[s] = *(const bf16x8*)(base + s * 1024);
            f32x4 a0 = {0.f, 0.f, 0.f, 0.f}, a1 = {0.f, 0.f, 0.f, 0.f};
            #pragma unroll
            for (int s = 0; s < 8; s += 2) {     // two independent chains
                a0 = __builtin_amdgcn_mfma_f32_16x16x32_bf16(afrag[s], b[s], a0, 0, 0, 0);
                a1 = __builtin_amdgcn_mfma_f32_16x16x32_bf16(afrag[s + 1], b[s + 1], a1, 0, 0, 0);
            }
            const int code = c * 32 + g * 16 + l15;
            const float nk = nrmS[code];
            #pragma unroll
            for (int r = 0; r < 4; ++r) {
                const float sc = fmaf(-2.f, a0[r] + a1[r], nk);
                if (sc < b1v[r]) {
                    b3v[r] = b2v[r]; b2v[r] = b1v[r]; b2i[r] = b1i[r];
                    b1v[r] = sc; b1i[r] = code;
                } else if (sc < b2v[r]) {
                    b3v[r] = b2v[r]; b2v[r] = sc; b2i[r] = code;
                } else if (sc < b3v[r]) {
                    b3v[r] = sc;
                }
            }
        }
    };

    // ---- pipelined chunk loop: 32 chunks, 2-deep prefetch, 3 buffers ----
    __syncthreads();            // nrm/cnt/esc visible; vmcnt drained to 0
    STAGE(0, 0);                // 4 outstanding
    STAGE(1, 1);                // 8 outstanding
    for (int c = 0; c < 30; ++c) {
        asm volatile("s_waitcnt vmcnt(4)" ::: "memory");   // chunk c landed
        __builtin_amdgcn_s_barrier();                       // all waves' quarters
        __builtin_amdgcn_sched_barrier(0);
        STAGE(c + 2, (c + 2) % 3);   // buf[(c-1)%3] free: all computed c-1
        __builtin_amdgcn_sched_barrier(0);
        COMPUTE(c, c % 3);
    }
    asm volatile("s_waitcnt vmcnt(4)" ::: "memory");
    __builtin_amdgcn_s_barrier();
    __builtin_amdgcn_sched_barrier(0);
    COMPUTE(30, 0);             // 30 % 3
    asm volatile("s_waitcnt vmcnt(0)" ::: "memory");
    __builtin_amdgcn_s_barrier();
    __builtin_amdgcn_sched_barrier(0);
    COMPUTE(31, 1);             // 31 % 3

    // ---- emission with FINAL block threshold ----
    #pragma unroll
    for (int r = 0; r < 4; ++r) {
        float m = b1v[r];
        #pragma unroll
        for (int off = 1; off < 16; off <<= 1)
            m = fminf(m, __shfl_xor(m, off, 16));
        const int rowL = w * 16 + lq * 4 + r;
        if (l15 == 0) rowminS[rowL] = m;
        const float thr = m + MARGIN;
        if (b1v[r] <= thr) {
            const int p = atomicAdd(&cntS[rowL], 1);
            if (p < CAP) candS[rowL][p] = packKey(b1v[r], b1i[r]);
        }
        if (b2v[r] <= thr) {
            const int p = atomicAdd(&cntS[rowL], 1);
            if (p < CAP) candS[rowL][p] = packKey(b2v[r], b2i[r]);
        }
        if (b3v[r] <= thr)
            atomicOr(&escS[rowL], 1u << l15);   // lane may have dropped a 4th+
    }
    __syncthreads();

    // ---- resolve epilogue: wave handles its own 16 rows ----
    double lacc = 0.0;
    for (int rr = 0; rr < 16; ++rr) {
        const int rowL = w * 16 + rr;
        const int row = row0 + rowL;
        const float4 x4 = *(const float4*)&X[(size_t)row * Ddim + l * 4];
        const int n = cntS[rowL];
        const unsigned em = escS[rowL];

        // shuffle-parallel exact fp32 rescore (one code, all 64 lanes)
        auto rescoreS = [&](int code) -> float {
            const float4 e4 = *(const float4*)&ET[(size_t)code * Ddim + l * 4];
            float d = x4.x * e4.x;
            d = fmaf(x4.y, e4.y, d);
            d = fmaf(x4.z, e4.z, d);
            d = fmaf(x4.w, e4.w, d);
            #pragma unroll
            for (int off = 1; off < 64; off <<= 1) d += __shfl_xor(d, off, 64);
            return nrmS[code] - 2.f * d;
        };
        // per-lane serial exact fp32 score (lane-parallel over codes)
        auto laneDot = [&](int cd) -> float {
            const float* ep = ET + (size_t)cd * Ddim;
            const float* xp = X + (size_t)row * Ddim;
            float s0 = 0.f, s1 = 0.f, s2 = 0.f, s3 = 0.f;
            for (int d0 = 0; d0 < 64; ++d0) {
                const float4 e4 = *(const float4*)(ep + d0 * 4);
                const float4 xx = *(const float4*)(xp + d0 * 4);
                s0 = fmaf(xx.x, e4.x, s0); s1 = fmaf(xx.y, e4.y, s1);
                s2 = fmaf(xx.z, e4.z, s2); s3 = fmaf(xx.w, e4.w, s3);
            }
            return nrmS[cd] - 2.f * ((s0 + s1) + (s2 + s3));
        };

        int code;
        if (n == 1 && em == 0) {
            code = (int)(candS[rowL][0] & 0xffffffffu);   // provably the argmin
        } else if (n >= 1 && n <= CAP) {
            float bS = 3.4e38f; int bC = 0x7fffffff;
            for (int j = 0; j < n; ++j) {
                const int cd = (int)(candS[rowL][j] & 0xffffffffu);
                const float s = rescoreS(cd);
                if (s < bS || (s == bS && cd < bC)) { bS = s; bC = cd; }
            }
            unsigned m2 = em;
            while (m2) {   // escalated lane: rescan its 64 codes, lane-parallel
                const int c15 = __ffs(m2) - 1; m2 &= m2 - 1;
                const int cd = l * 16 + c15;
                u64 k = packKey(laneDot(cd), cd);
                #pragma unroll
                for (int off = 1; off < 64; off <<= 1) {
                    const u64 o = __shfl_xor(k, off, 64);
                    if (o < k) k = o;
                }
                const float s = unpackScore(k);
                const int cd2 = (int)(k & 0xffffffffu);
                if (s < bS || (s == bS && cd2 < bC)) { bS = s; bC = cd2; }
            }
            code = bC;
        } else {   // unreachable (CAP structural); cheap lane-parallel scan
            u64 k = ~0ULL;
            for (int i = 0; i < 16; ++i) {
                const int cd = i * 64 + l;
                const u64 k2 = packKey(laneDot(cd), cd);
                if (k2 < k) k = k2;
            }
            #pragma unroll
            for (int off = 1; off < 64; off <<= 1) {
                const u64 o = __shfl_xor(k, off, 64);
                if (o < k) k = o;
            }
            code = (int)(k & 0xffffffffu);
        }

        const float4 q4 = *(const float4*)&ET[(size_t)code * Ddim + l * 4];
        *(float4*)&out[(size_t)row * Ddim + l * 4] = q4;
        const double dx = (double)(q4.x - x4.x), dy = (double)(q4.y - x4.y);
        const double dz = (double)(q4.z - x4.z), dw = (double)(q4.w - x4.w);
        lacc += dx * dx + dy * dy + dz * dz + dw * dw;
    }
    #pragma unroll
    for (int off = 32; off; off >>= 1) lacc += __shfl_down(lacc, off, 64);
    if (l == 0) lred[w] = lacc;
    __syncthreads();
    if (t == 0)
        partials[blockIdx.x] = lred[0] + lred[1] + lred[2] + lred[3];
}

// ---- final loss ----
__global__ __launch_bounds__(256)
void vq_lossk(const double* __restrict__ partials, float* __restrict__ lossOut) {
    __shared__ double red[4];
    double v = 0.0;
    for (int i = threadIdx.x; i < 512; i += 256) v += partials[i];
    #pragma unroll
    for (int off = 32; off; off >>= 1) v += __shfl_down(v, off, 64);
    const int lane = threadIdx.x & 63, grp = threadIdx.x >> 6;
    if (lane == 0) red[grp] = v;
    __syncthreads();
    if (threadIdx.x == 0)
        lossOut[0] = (float)(1.25 * (red[0] + red[1] + red[2] + red[3]) /
                             (double)((size_t)Mrows * Ddim));
}

// ===========================================================================
extern "C" void kernel_launch(void* const* d_in, const int* in_sizes, int n_in,
                              void* d_out, int out_size, void* d_ws, size_t ws_size,
                              hipStream_t stream) {
    const float* X = (const float*)d_in[0];
    const float* E = (const float*)d_in[1];
    float* out = (float*)d_out;
    char* ws = (char*)d_ws;

    // workspace: partials 4KB | ET 1MB | ETbf 512KB | norms 4KB  (~1.5MB)
    const size_t partB = 512 * 8;
    const size_t etB   = (size_t)Kcode * Ddim * 4;
    const size_t etbfB = (size_t)Kcode * Ddim * 2;
    char* p = ws;
    double* partials = (double*)p;  p += partB;
    float*  ET       = (float*)p;   p += etB;
    char*   ETbf     = p;           p += etbfB;
    float*  norms    = (float*)p;

    vq_prep<<<16, 256, 0, stream>>>(E, ET, ETbf, norms);
    vq_fused<<<Mrows / 64, 256, 0, stream>>>(X, ETbf, ET, norms, out, partials);
    vq_lossk<<<1, 256, 0, stream>>>(partials, out + (size_t)Mrows * Ddim);
}